// Round 10
// baseline (49.329 us; speedup 1.0000x reference)
//
#include <hip/hip_runtime.h>

#define TT 64
#define DIM 13
#define NSEQ 128
#define NWAVE 2080           // sum over a of ceil((127-a)/4): 4 partner pairs per wave
#define NSTEP (TT + 16 - 1)  // 79 anti-diagonal steps (16 lane-groups x 4 cols x 64 rows)
#define INFV 1e10f
#define C_EXP 14.4269504088896f     // log2(e)/gamma ; S = R*C_EXP (scaled log2 domain)
#define C_INV 0.06931471805599453f  // gamma*ln2

typedef _Float16 h2 __attribute__((ext_vector_type(2)));

__device__ __forceinline__ float fdot2(h2 a, h2 b, float c) {
    return __builtin_amdgcn_fdot2(a, b, c, false);
}
__device__ __forceinline__ h2 mkh2(float a, float b) {
    h2 p; p.x = (_Float16)a; p.y = (_Float16)b; return p;
}
__device__ __forceinline__ h2 bch2(unsigned u) { return __builtin_bit_cast(h2, u); }
// lane i <- lane i-1 within each 16-lane row (row_shr:1 = 0x111); lane sj==0 of
// each row gets old = INFV (bound_ctrl=false). Full-rate VALU, no DS op, no cndmask.
__device__ __forceinline__ float rowshr1_inf(float x) {
    int r = __builtin_amdgcn_update_dpp(__builtin_bit_cast(int, INFV),
                                        __builtin_bit_cast(int, x),
                                        0x111, 0xf, 0xf, false);
    return __builtin_bit_cast(float, r);
}
// one softmin+update: S <- C*acc + softmin(S, lf, dg) in scaled-log2 domain
__device__ __forceinline__ float smstep(float S, float lf, float dg, float acc) {
    float m  = fminf(fminf(S, lf), dg);                 // v_min3_f32
    float md = __builtin_amdgcn_fmed3f(S, lf, dg);
    float M  = fmaxf(fmaxf(S, lf), dg);                 // v_max3_f32
    float s  = 1.0f + __builtin_amdgcn_exp2f(m - md) + __builtin_amdgcn_exp2f(m - M);
    return fmaf(acc, C_EXP, m - __builtin_amdgcn_logf(s));   // v_log_f32 = log2
}
__device__ __forceinline__ int Tq4(int N) {   // sum_{n=1..N} ceil(n/4)
    int q = N >> 2, r = N & 3;
    return 2 * q * (q + 1) + r * (q + 1);
}

__global__ __launch_bounds__(256, 2) void sdtw_pairs(const float* __restrict__ xxx,
                                                     const float* __restrict__ yyy,
                                                     float* __restrict__ simR) {
    // One x-stream (seq a) per wave, comp-major [7][64]; all 4 quarter-waves read
    // identical addresses per step (LDS broadcast) -> conflict-free.
    __shared__ unsigned xl[4][7 * TT];
    const int wave = threadIdx.x >> 6;
    const int lane = threadIdx.x & 63;
    const int quarter = lane >> 4;
    const int sj = lane & 15;                     // lane owns columns 4sj..4sj+3
    const int t = blockIdx.x * 4 + wave;          // wave id 0..2079

    // decode t -> (a, q): waves before row a = NWAVE - Tq4(127-a)  (R8-verified)
    int a = 127 - (int)sqrtf(8.0f * (float)(NWAVE - t));
    if (a < 0) a = 0;
    if (a > 126) a = 126;
    while (NWAVE - Tq4(127 - a) > t) a--;
    while (a < 126 && NWAVE - Tq4(127 - (a + 1)) <= t) a++;
    const int q = t - (NWAVE - Tq4(127 - a));
    const int b0 = a + 1 + 4 * q;
    const int b = (b0 + quarter < 128) ? b0 + quarter : 127;  // clamped dups: benign
                                                              // same-value rewrites
    // y side: columns 4sj..4sj+3 of seq b, in registers
    h2 yA[7], yB[7], yC[7], yD[7];
    float sqA = 0.f, sqB = 0.f, sqC = 0.f, sqD = 0.f;
    {
        const float* fb = ((b < 64) ? xxx + (size_t)b * TT * DIM
                                    : yyy + (size_t)(b - 64) * TT * DIM) + (4 * sj) * DIM;
        float vA[DIM], vB[DIM], vC[DIM], vD[DIM];
#pragma unroll
        for (int c = 0; c < DIM; c++) {
            vA[c] = fb[c];            sqA += vA[c] * vA[c];
            vB[c] = fb[DIM + c];      sqB += vB[c] * vB[c];
            vC[c] = fb[2 * DIM + c];  sqC += vC[c] * vC[c];
            vD[c] = fb[3 * DIM + c];  sqD += vD[c] * vD[c];
        }
#pragma unroll
        for (int c = 0; c < 6; c++) {
            yA[c] = mkh2(vA[2 * c], vA[2 * c + 1]);
            yB[c] = mkh2(vB[2 * c], vB[2 * c + 1]);
            yC[c] = mkh2(vC[2 * c], vC[2 * c + 1]);
            yD[c] = mkh2(vD[2 * c], vD[2 * c + 1]);
        }
        yA[6] = mkh2(vA[12], 1.0f);
        yB[6] = mkh2(vB[12], 1.0f);
        yC[6] = mkh2(vC[12], 1.0f);
        yD[6] = mkh2(vD[12], 1.0f);
    }

    // x side (seq a, shared by all 4 quarters): lane stages its row; pairs (-2x),
    // last (-2x12, sqx)
    {
        const float* fx = ((a < 64) ? xxx + (size_t)a * TT * DIM
                                    : yyy + (size_t)(a - 64) * TT * DIM) + lane * DIM;
        float xv[DIM], sqx = 0.f;
#pragma unroll
        for (int c = 0; c < DIM; c++) { xv[c] = fx[c]; sqx += xv[c] * xv[c]; }
        unsigned* dst = &xl[wave][lane];
#pragma unroll
        for (int c = 0; c < 6; c++)
            dst[c * TT] = __builtin_bit_cast(unsigned, mkh2(-2.f * xv[2 * c], -2.f * xv[2 * c + 1]));
        dst[6 * TT] = __builtin_bit_cast(unsigned, mkh2(-2.f * xv[12], sqx));
    }
    __syncthreads();

    // DP: at step k, lane computes cells (i, 4sj+{0,1,2,3}), i = k - sj.
    //   A: up=SA, left=lane-1's SD (dpp row_shr, INFV at sj==0), diag=prev left
    //   B/C/D: up=own S, left=new S of prev col, diag=old S of prev col (in-lane)
    // No validity predicates: inactive lanes ride at ~INFV; exp2 terms underflow;
    // wrapped rows feed only invalid cells (R9-verified pattern).
    const unsigned* xp = xl[wave];
    float SA = INFV, SB = INFV, SC = INFV, SD = INFV;
    float dgA = (sj == 0) ? 0.f : INFV;     // corner for cell (0,0)
    int ic = (-sj) & (TT - 1);

#pragma unroll 2
    for (int k = 0; k < NSTEP; k++) {
        unsigned w0 = xp[ic];
        unsigned w1 = xp[ic + 1 * TT];
        unsigned w2 = xp[ic + 2 * TT];
        unsigned w3 = xp[ic + 3 * TT];
        unsigned w4 = xp[ic + 4 * TT];
        unsigned w5 = xp[ic + 5 * TT];
        unsigned w6 = xp[ic + 6 * TT];
        ic = (ic + 1) & (TT - 1);

        float aA = sqA, aB = sqB, aC = sqC, aD = sqD;
        aA = fdot2(yA[0], bch2(w0), aA); aB = fdot2(yB[0], bch2(w0), aB);
        aC = fdot2(yC[0], bch2(w0), aC); aD = fdot2(yD[0], bch2(w0), aD);
        aA = fdot2(yA[1], bch2(w1), aA); aB = fdot2(yB[1], bch2(w1), aB);
        aC = fdot2(yC[1], bch2(w1), aC); aD = fdot2(yD[1], bch2(w1), aD);
        aA = fdot2(yA[2], bch2(w2), aA); aB = fdot2(yB[2], bch2(w2), aB);
        aC = fdot2(yC[2], bch2(w2), aC); aD = fdot2(yD[2], bch2(w2), aD);
        aA = fdot2(yA[3], bch2(w3), aA); aB = fdot2(yB[3], bch2(w3), aB);
        aC = fdot2(yC[3], bch2(w3), aC); aD = fdot2(yD[3], bch2(w3), aD);
        aA = fdot2(yA[4], bch2(w4), aA); aB = fdot2(yB[4], bch2(w4), aB);
        aC = fdot2(yC[4], bch2(w4), aC); aD = fdot2(yD[4], bch2(w4), aD);
        aA = fdot2(yA[5], bch2(w5), aA); aB = fdot2(yB[5], bch2(w5), aB);
        aC = fdot2(yC[5], bch2(w5), aC); aD = fdot2(yD[5], bch2(w5), aD);
        aA = fdot2(yA[6], bch2(w6), aA); aB = fdot2(yB[6], bch2(w6), aB);
        aC = fdot2(yC[6], bch2(w6), aC); aD = fdot2(yD[6], bch2(w6), aD);

        float lfA = rowshr1_inf(SD);        // lane-1's col-D state; INFV at sj==0

        float oA = SA; SA = smstep(SA, lfA, dgA, aA);
        float oB = SB; SB = smstep(SB, SA, oA, aB);
        float oC = SC; SC = smstep(SC, SB, oB, aC);
        SD = smstep(SD, SC, oC, aD);
        dgA = lfA;
    }

    if (sj == 15) {                          // col 63 = D column; final cell at k=78
        const float r = SD * C_INV;
        simR[a * NSEQ + b] = r;
        simR[b * NSEQ + a] = r;
    }
}

// one wave per row: lse(row) - positive ; result parked in the (unused) diagonal
__global__ void row_lse(float* __restrict__ simR) {
    const int r = blockIdx.x;
    const int lane = threadIdx.x;
    const float* rowp = simR + r * NSEQ;
    float v0 = (lane == r) ? 0.f : 2.f * rowp[lane];
    const int c1 = lane + 64;
    float v1 = (c1 == r) ? 0.f : 2.f * rowp[c1];
    float mx = fmaxf(v0, v1);
#pragma unroll
    for (int o = 32; o; o >>= 1) mx = fmaxf(mx, __shfl_xor(mx, o));
    float s = __builtin_amdgcn_exp2f((v0 - mx) * 1.4426950408889634f)
            + __builtin_amdgcn_exp2f((v1 - mx) * 1.4426950408889634f);
#pragma unroll
    for (int o = 32; o; o >>= 1) s += __shfl_xor(s, o);
    if (lane == 0) {
        const int i = r & 63;
        float pos = 2.f * simR[i * NSEQ + i + 64];
        simR[r * NSEQ + r] = mx + 0.6931471805599453f * __builtin_amdgcn_logf(s) - pos;
    }
}

__global__ void final_loss(const float* __restrict__ simR, float* __restrict__ out) {
    __shared__ float red[NSEQ];
    const int tid = threadIdx.x;
    red[tid] = simR[tid * NSEQ + tid];
    __syncthreads();
    if (tid == 0) {
        float tsum = 0.f;
        for (int c = 0; c < NSEQ; c++) tsum += red[c];
        out[0] = tsum / (float)NSEQ;
    }
}

extern "C" void kernel_launch(void* const* d_in, const int* in_sizes, int n_in,
                              void* d_out, int out_size, void* d_ws, size_t ws_size,
                              hipStream_t stream) {
    const float* xxx = (const float*)d_in[0];
    const float* yyy = (const float*)d_in[1];
    float* out = (float*)d_out;
    float* simR = (float*)d_ws;   // 16384 floats = 64 KB

    sdtw_pairs<<<NWAVE / 4, 256, 0, stream>>>(xxx, yyy, simR);
    row_lse<<<NSEQ, 64, 0, stream>>>(simR);
    final_loss<<<1, NSEQ, 0, stream>>>(simR, out);
}

// Round 11
// 42.971 us; speedup vs baseline: 1.1480x; 1.1480x over previous
//
#include <hip/hip_runtime.h>

#define TT 64
#define DIM 13
#define NSEQ 128
#define NPAIRS 8128          // 128*127/2 upper-triangle pairs (soft-DTW symmetric)
#define NWAVE 4064           // 2 pairs per wave (one per 32-lane half)
#define NSTEP (TT + 32 - 1)  // 95 anti-diagonal steps (32 lane-columns x 64 rows)
#define INFV 1e10f
#define C_EXP 14.4269504088896f     // log2(e)/gamma ; S = R*C_EXP (scaled log2 domain)
#define C_INV 0.06931471805599453f  // gamma*ln2

typedef _Float16 h2 __attribute__((ext_vector_type(2)));

__device__ __forceinline__ float fdot2(h2 a, h2 b, float c) {
    return __builtin_amdgcn_fdot2(a, b, c, false);
}
__device__ __forceinline__ h2 mkh2(float a, float b) {
    h2 p; p.x = (_Float16)a; p.y = (_Float16)b; return p;
}
__device__ __forceinline__ h2 bch2(unsigned u) { return __builtin_bit_cast(h2, u); }
// lane i <- lane i-1 (wave_shr:1), lane 0 <- INFV; full-rate VALU, no DS op
__device__ __forceinline__ float shr1_inf(float x) {
    int r = __builtin_amdgcn_update_dpp(__builtin_bit_cast(int, INFV),
                                        __builtin_bit_cast(int, x),
                                        0x138, 0xf, 0xf, false);
    return __builtin_bit_cast(float, r);
}
// one softmin+update: S <- C*acc + softmin(S, lf, dg) in scaled-log2 domain
__device__ __forceinline__ float smstep(float S, float lf, float dg, float acc) {
    float m  = fminf(fminf(S, lf), dg);                 // v_min3_f32
    float md = __builtin_amdgcn_fmed3f(S, lf, dg);
    float M  = fmaxf(fmaxf(S, lf), dg);                 // v_max3_f32
    float s  = 1.0f + __builtin_amdgcn_exp2f(m - md) + __builtin_amdgcn_exp2f(m - M);
    return fmaf(acc, C_EXP, m - __builtin_amdgcn_logf(s));   // v_log_f32 = log2
}

__global__ __launch_bounds__(256) void sdtw_pairs(const float* __restrict__ xxx,
                                                  const float* __restrict__ yyy,
                                                  float* __restrict__ simR) {
    // Per wave: 2 pairs (lane halves). Lane (half, sj) owns DP columns 2sj, 2sj+1
    // of its half's pair. x staged comp-major: [7 comps][2 halves * 64 rows].
    __shared__ unsigned xl[4][7 * 2 * TT];
    const int wave = threadIdx.x >> 6;
    const int lane = threadIdx.x & 63;
    const int half = lane >> 5;
    const int sj   = lane & 31;
    const int p = 2 * (blockIdx.x * 4 + wave) + half;   // pair id 0..8127

    // decode p -> (a,b), a<b ; pairs before row a: a*(255-a)/2
    int a = (int)((255.0f - sqrtf(65025.0f - 8.0f * (float)p)) * 0.5f);
    if (a < 0) a = 0;
    if (a > 126) a = 126;
    while (a * (255 - a) / 2 > p) a--;
    while ((a + 1) * (254 - a) / 2 <= p) a++;
    const int b = a + 1 + (p - a * (255 - a) / 2);

    // y side: columns 2sj, 2sj+1 of seq b, in registers
    h2 yA[7], yB[7];
    float sqyA = 0.f, sqyB = 0.f;
    {
        const float* fb = ((b < 64) ? xxx + (size_t)b * TT * DIM
                                    : yyy + (size_t)(b - 64) * TT * DIM) + (2 * sj) * DIM;
        float vA[DIM], vB[DIM];
#pragma unroll
        for (int c = 0; c < DIM; c++) {
            vA[c] = fb[c];        sqyA += vA[c] * vA[c];
            vB[c] = fb[DIM + c];  sqyB += vB[c] * vB[c];
        }
#pragma unroll
        for (int c = 0; c < 6; c++) {
            yA[c] = mkh2(vA[2 * c], vA[2 * c + 1]);
            yB[c] = mkh2(vB[2 * c], vB[2 * c + 1]);
        }
        yA[6] = mkh2(vA[12], 1.0f);
        yB[6] = mkh2(vB[12], 1.0f);
    }

    // x side (seq a): rows sj and sj+32 staged; pairs (-2x), last (-2x12, sqx)
    {
        const float* fa = (a < 64) ? xxx + (size_t)a * TT * DIM
                                   : yyy + (size_t)(a - 64) * TT * DIM;
        unsigned* xw = xl[wave];
#pragma unroll
        for (int rr = 0; rr < 2; rr++) {
            const int r = sj + 32 * rr;
            const float* fx = fa + r * DIM;
            float xv[DIM], sqx = 0.f;
#pragma unroll
            for (int c = 0; c < DIM; c++) { xv[c] = fx[c]; sqx += xv[c] * xv[c]; }
            unsigned* dst = xw + half * TT + r;
#pragma unroll
            for (int c = 0; c < 6; c++)
                dst[c * 128] = __builtin_bit_cast(unsigned, mkh2(-2.f * xv[2 * c], -2.f * xv[2 * c + 1]));
            dst[6 * 128] = __builtin_bit_cast(unsigned, mkh2(-2.f * xv[12], sqx));
        }
    }
    __syncthreads();

    // DP: at step k, lane computes cells (i, 2sj) and (i, 2sj+1), i = k - sj.
    //   A: up = own SA; left = lane-1's SB (prev step) via dpp; diag = prev left.
    //   B: up = own SB; left = SA (just computed); diag = SA before update.
    // x-words for step k+1 are prefetched into registers before step k's math,
    // hiding the ds_read latency under ~150 cy of VALU/trans work.
    const unsigned* xp = xl[wave] + half * TT;
    float SA = INFV, SB = INFV;
    float dgA = (sj == 0) ? 0.f : INFV;     // corner for cell (0,0)
    const bool col0 = (sj == 0);
    int ic = (-sj) & (TT - 1);

    unsigned w[7];
#pragma unroll
    for (int c = 0; c < 7; c++) w[c] = xp[ic + c * 128];
    ic = (ic + 1) & (TT - 1);

#pragma unroll 2
    for (int k = 0; k < NSTEP; k++) {
        unsigned nw[7];
#pragma unroll
        for (int c = 0; c < 7; c++) nw[c] = xp[ic + c * 128];   // prefetch k+1
        ic = (ic + 1) & (TT - 1);

        float aA = sqyA, aB = sqyB;
        aA = fdot2(yA[0], bch2(w[0]), aA); aB = fdot2(yB[0], bch2(w[0]), aB);
        aA = fdot2(yA[1], bch2(w[1]), aA); aB = fdot2(yB[1], bch2(w[1]), aB);
        aA = fdot2(yA[2], bch2(w[2]), aA); aB = fdot2(yB[2], bch2(w[2]), aB);
        aA = fdot2(yA[3], bch2(w[3]), aA); aB = fdot2(yB[3], bch2(w[3]), aB);
        aA = fdot2(yA[4], bch2(w[4]), aA); aB = fdot2(yB[4], bch2(w[4]), aB);
        aA = fdot2(yA[5], bch2(w[5]), aA); aB = fdot2(yB[5], bch2(w[5]), aB);
        aA = fdot2(yA[6], bch2(w[6]), aA); aB = fdot2(yB[6], bch2(w[6]), aB);

        float lfA = shr1_inf(SB);           // lane-1's SB; crosses half boundary:
        lfA = col0 ? INFV : lfA;            // forced to INFV at col 0 of each pair

        float SAold = SA;
        SA = smstep(SA, lfA, dgA, aA);      // cell A
        SB = smstep(SB, SA, SAold, aB);     // cell B (left=new SA, diag=old SA)
        dgA = lfA;

#pragma unroll
        for (int c = 0; c < 7; c++) w[c] = nw[c];
    }

    if (sj == 31) {                          // SB = R(63,63) of this half's pair
        const float r = SB * C_INV;
        simR[a * NSEQ + b] = r;
        simR[b * NSEQ + a] = r;
    }
}

// fused loss: row-wise stabilized LSE (8 lanes per row) + positives + mean.
// One block, 1024 threads; deterministic reduction order.
__global__ __launch_bounds__(1024) void loss_reduce(const float* __restrict__ simR,
                                                    float* __restrict__ out) {
    __shared__ float rsum[NSEQ];
    const int tid = threadIdx.x;
    const int r  = tid >> 3;       // row 0..127
    const int l8 = tid & 7;        // 8 lanes per row
    const float* rowp = simR + r * NSEQ;

    float v[16];
#pragma unroll
    for (int c = 0; c < 16; c++) {
        const int col = l8 + 8 * c;
        v[c] = (col == r) ? 0.f : 2.f * rowp[col];   // sim = R/ENERGY, diag zeroed
    }
    float mx = v[0];
#pragma unroll
    for (int c = 1; c < 16; c++) mx = fmaxf(mx, v[c]);
#pragma unroll
    for (int o = 1; o <= 4; o <<= 1) mx = fmaxf(mx, __shfl_xor(mx, o));
    float s = 0.f;
#pragma unroll
    for (int c = 0; c < 16; c++) s += __builtin_amdgcn_exp2f((v[c] - mx) * 1.4426950408889634f);
#pragma unroll
    for (int o = 1; o <= 4; o <<= 1) s += __shfl_xor(s, o);
    if (l8 == 0) {
        const int i = r & 63;
        const float pos = 2.f * simR[i * NSEQ + i + 64];
        rsum[r] = mx + 0.6931471805599453f * __builtin_amdgcn_logf(s) - pos;
    }
    __syncthreads();
    if (tid < 64) {
        float t = rsum[tid] + rsum[tid + 64];
#pragma unroll
        for (int o = 32; o; o >>= 1) t += __shfl_xor(t, o);
        if (tid == 0) out[0] = t / (float)NSEQ;
    }
}

extern "C" void kernel_launch(void* const* d_in, const int* in_sizes, int n_in,
                              void* d_out, int out_size, void* d_ws, size_t ws_size,
                              hipStream_t stream) {
    const float* xxx = (const float*)d_in[0];
    const float* yyy = (const float*)d_in[1];
    float* out = (float*)d_out;
    float* simR = (float*)d_ws;   // 16384 floats = 64 KB

    sdtw_pairs<<<NWAVE / 4, 256, 0, stream>>>(xxx, yyy, simR);
    loss_reduce<<<1, 1024, 0, stream>>>(simR, out);
}

// Round 12
// 42.555 us; speedup vs baseline: 1.1592x; 1.0098x over previous
//
#include <hip/hip_runtime.h>

#define TT 64
#define DIM 13
#define NSEQ 128
#define NPAIRS 8128          // 128*127/2 upper-triangle pairs (soft-DTW symmetric)
#define NWAVE 4064           // 2 pairs per wave (one per 32-lane half)
#define NSTEP (TT + 32 - 1)  // 95 anti-diagonal steps (32 lane-columns x 64 rows)
#define INFV 1e10f
#define C_EXP 14.4269504088896f     // log2(e)/gamma ; S = R*C_EXP (scaled log2 domain)
#define C_INV 0.06931471805599453f  // gamma*ln2

typedef _Float16 h2 __attribute__((ext_vector_type(2)));

__device__ __forceinline__ float fdot2(h2 a, h2 b, float c) {
    return __builtin_amdgcn_fdot2(a, b, c, false);
}
__device__ __forceinline__ h2 mkh2(float a, float b) {
    h2 p; p.x = (_Float16)a; p.y = (_Float16)b; return p;
}
__device__ __forceinline__ h2 bch2(unsigned u) { return __builtin_bit_cast(h2, u); }
// lane i <- lane i-1 (wave_shr:1), lane 0 <- INFV; full-rate VALU, no DS op
__device__ __forceinline__ float shr1_inf(float x) {
    int r = __builtin_amdgcn_update_dpp(__builtin_bit_cast(int, INFV),
                                        __builtin_bit_cast(int, x),
                                        0x138, 0xf, 0xf, false);
    return __builtin_bit_cast(float, r);
}
// one softmin+update: S <- C*acc + softmin(S, lf, dg) in scaled-log2 domain
__device__ __forceinline__ float smstep(float S, float lf, float dg, float acc) {
    float m  = fminf(fminf(S, lf), dg);                 // v_min3_f32
    float md = __builtin_amdgcn_fmed3f(S, lf, dg);
    float M  = fmaxf(fmaxf(S, lf), dg);                 // v_max3_f32
    float s  = 1.0f + __builtin_amdgcn_exp2f(m - md) + __builtin_amdgcn_exp2f(m - M);
    return fmaf(acc, C_EXP, m - __builtin_amdgcn_logf(s));   // v_log_f32 = log2
}

__global__ __launch_bounds__(128) void sdtw_pairs(const float* __restrict__ xxx,
                                                  const float* __restrict__ yyy,
                                                  float* __restrict__ simR) {
    // 128-thread blocks (2 waves) for fine-grained CU scheduling. Per wave: 2
    // pairs (lane halves). Lane (half, sj) owns DP columns 2sj, 2sj+1 of its
    // half's pair. x staged comp-major: [7 comps][2 halves * 64 rows].
    __shared__ unsigned xl[2][7 * 2 * TT];
    const int wave = threadIdx.x >> 6;
    const int lane = threadIdx.x & 63;
    const int half = lane >> 5;
    const int sj   = lane & 31;
    const int p = 2 * (blockIdx.x * 2 + wave) + half;   // pair id 0..8127

    // decode p -> (a,b), a<b ; pairs before row a: a*(255-a)/2
    int a = (int)((255.0f - sqrtf(65025.0f - 8.0f * (float)p)) * 0.5f);
    if (a < 0) a = 0;
    if (a > 126) a = 126;
    while (a * (255 - a) / 2 > p) a--;
    while ((a + 1) * (254 - a) / 2 <= p) a++;
    const int b = a + 1 + (p - a * (255 - a) / 2);

    // y side: columns 2sj, 2sj+1 of seq b, in registers
    h2 yA[7], yB[7];
    float sqyA = 0.f, sqyB = 0.f;
    {
        const float* fb = ((b < 64) ? xxx + (size_t)b * TT * DIM
                                    : yyy + (size_t)(b - 64) * TT * DIM) + (2 * sj) * DIM;
        float vA[DIM], vB[DIM];
#pragma unroll
        for (int c = 0; c < DIM; c++) {
            vA[c] = fb[c];        sqyA += vA[c] * vA[c];
            vB[c] = fb[DIM + c];  sqyB += vB[c] * vB[c];
        }
#pragma unroll
        for (int c = 0; c < 6; c++) {
            yA[c] = mkh2(vA[2 * c], vA[2 * c + 1]);
            yB[c] = mkh2(vB[2 * c], vB[2 * c + 1]);
        }
        yA[6] = mkh2(vA[12], 1.0f);
        yB[6] = mkh2(vB[12], 1.0f);
    }

    // x side (seq a): rows sj and sj+32 staged; pairs (-2x), last (-2x12, sqx)
    {
        const float* fa = (a < 64) ? xxx + (size_t)a * TT * DIM
                                   : yyy + (size_t)(a - 64) * TT * DIM;
        unsigned* xw = xl[wave];
#pragma unroll
        for (int rr = 0; rr < 2; rr++) {
            const int r = sj + 32 * rr;
            const float* fx = fa + r * DIM;
            float xv[DIM], sqx = 0.f;
#pragma unroll
            for (int c = 0; c < DIM; c++) { xv[c] = fx[c]; sqx += xv[c] * xv[c]; }
            unsigned* dst = xw + half * TT + r;
#pragma unroll
            for (int c = 0; c < 6; c++)
                dst[c * 128] = __builtin_bit_cast(unsigned, mkh2(-2.f * xv[2 * c], -2.f * xv[2 * c + 1]));
            dst[6 * 128] = __builtin_bit_cast(unsigned, mkh2(-2.f * xv[12], sqx));
        }
    }
    __syncthreads();

    // DP: at step k, lane computes cells (i, 2sj) and (i, 2sj+1), i = k - sj.
    //   A: up = own SA; left = lane-1's SB (prev step) via dpp; diag = prev left.
    //   B: up = own SB; left = SA (just computed); diag = SA before update.
    // No validity predicates: inactive lanes ride at ~INFV; exp2 terms underflow;
    // wrapped x rows feed only invalid cells.
    const unsigned* xp = xl[wave] + half * TT;
    float SA = INFV, SB = INFV;
    float dgA = (sj == 0) ? 0.f : INFV;     // corner for cell (0,0)
    const bool col0 = (sj == 0);
    int ic = (-sj) & (TT - 1);

#pragma unroll 2
    for (int k = 0; k < NSTEP; k++) {
        unsigned w0 = xp[ic];
        unsigned w1 = xp[ic + 1 * 128];
        unsigned w2 = xp[ic + 2 * 128];
        unsigned w3 = xp[ic + 3 * 128];
        unsigned w4 = xp[ic + 4 * 128];
        unsigned w5 = xp[ic + 5 * 128];
        unsigned w6 = xp[ic + 6 * 128];
        ic = (ic + 1) & (TT - 1);

        float aA = sqyA, aB = sqyB;
        aA = fdot2(yA[0], bch2(w0), aA); aB = fdot2(yB[0], bch2(w0), aB);
        aA = fdot2(yA[1], bch2(w1), aA); aB = fdot2(yB[1], bch2(w1), aB);
        aA = fdot2(yA[2], bch2(w2), aA); aB = fdot2(yB[2], bch2(w2), aB);
        aA = fdot2(yA[3], bch2(w3), aA); aB = fdot2(yB[3], bch2(w3), aB);
        aA = fdot2(yA[4], bch2(w4), aA); aB = fdot2(yB[4], bch2(w4), aB);
        aA = fdot2(yA[5], bch2(w5), aA); aB = fdot2(yB[5], bch2(w5), aB);
        aA = fdot2(yA[6], bch2(w6), aA); aB = fdot2(yB[6], bch2(w6), aB);

        float lfA = shr1_inf(SB);           // lane-1's SB; crosses half boundary:
        lfA = col0 ? INFV : lfA;            // forced to INFV at col 0 of each pair

        float SAold = SA;
        SA = smstep(SA, lfA, dgA, aA);      // cell A
        SB = smstep(SB, SA, SAold, aB);     // cell B (left=new SA, diag=old SA)
        dgA = lfA;
    }

    if (sj == 31) {                          // SB = R(63,63) of this half's pair
        const float r = SB * C_INV;
        simR[a * NSEQ + b] = r;
        simR[b * NSEQ + a] = r;
    }
}

// one wave per row: lse(row) - positive ; result parked in the (unused) diagonal
__global__ void row_lse(float* __restrict__ simR) {
    const int r = blockIdx.x;
    const int lane = threadIdx.x;
    const float* rowp = simR + r * NSEQ;
    float v0 = (lane == r) ? 0.f : 2.f * rowp[lane];
    const int c1 = lane + 64;
    float v1 = (c1 == r) ? 0.f : 2.f * rowp[c1];
    float mx = fmaxf(v0, v1);
#pragma unroll
    for (int o = 32; o; o >>= 1) mx = fmaxf(mx, __shfl_xor(mx, o));
    float s = __builtin_amdgcn_exp2f((v0 - mx) * 1.4426950408889634f)
            + __builtin_amdgcn_exp2f((v1 - mx) * 1.4426950408889634f);
#pragma unroll
    for (int o = 32; o; o >>= 1) s += __shfl_xor(s, o);
    if (lane == 0) {
        const int i = r & 63;
        float pos = 2.f * simR[i * NSEQ + i + 64];
        simR[r * NSEQ + r] = mx + 0.6931471805599453f * __builtin_amdgcn_logf(s) - pos;
    }
}

__global__ void final_loss(const float* __restrict__ simR, float* __restrict__ out) {
    __shared__ float red[NSEQ];
    const int tid = threadIdx.x;
    red[tid] = simR[tid * NSEQ + tid];
    __syncthreads();
    if (tid == 0) {
        float tsum = 0.f;
        for (int c = 0; c < NSEQ; c++) tsum += red[c];
        out[0] = tsum / (float)NSEQ;
    }
}

extern "C" void kernel_launch(void* const* d_in, const int* in_sizes, int n_in,
                              void* d_out, int out_size, void* d_ws, size_t ws_size,
                              hipStream_t stream) {
    const float* xxx = (const float*)d_in[0];
    const float* yyy = (const float*)d_in[1];
    float* out = (float*)d_out;
    float* simR = (float*)d_ws;   // 16384 floats = 64 KB

    sdtw_pairs<<<NWAVE / 2, 128, 0, stream>>>(xxx, yyy, simR);
    row_lse<<<NSEQ, 64, 0, stream>>>(simR);
    final_loss<<<1, NSEQ, 0, stream>>>(simR, out);
}